// Round 1
// baseline (192.146 us; speedup 1.0000x reference)
//
#include <hip/hip_runtime.h>
#include <stdint.h>

// WaveletSparsityPrior: 3-level Haar, loss = sum_lvl w_lvl * mean min(|c|, t_lvl)
// Two dispatches: pass_a -> pass_b (no memset: sub-histograms are plain-stored).
//
//  pass_a (grid 16x128, 256 thr): each WAVE owns an 8-row x 512-col strip.
//    All global loads are lane-contiguous float4 (lane i -> byte 16*i), Haar
//    tree in registers: level-1/2 in-lane, level-3 via shfl_xor(1) with the
//    work split even-lane=A-half / odd-lane=B-half (|coeff| invariant under
//    the column swap, so all 64 lanes are active). Per-block 512-bin LDS
//    histogram of |level-3 details| plain-stored to ghist[b][sub][512]
//    (overwrites 0xAA poison -> no memset needed). Block (0,0) zeroes d_out.
//    Speculative t = 0.2 (clip top) -> exact loss because sigma~1.0 ->
//    2.5*sigma clips (verified absmax=0 in prior session R1-R4).
//  pass_b (128 blocks x 64): sum 16 sub-hists (fully unrolled for MLP: this
//    grid is 0.5 wave/CU, pure latency), scan for median bin -> sigma
//    (bin-midpoint err <= 2e-3 << 2e-2 threshold) -> t -> finalize via
//    2 fp32 atomicAdds. Correction recompute only if t != 0.2 (never taken
//    for this input).
//
// ws layout: f32 [0,2048) partials[b*16+sub]; u32 [2048, +128*16*512) ghist.

static constexpr int BATCH = 128;
static constexpr int W = 512;
static constexpr int NBIN = 512;      // bin width 1/256 over [0,2)

__device__ __forceinline__ float block_reduce_sum(float v, float* lds) {
    #pragma unroll
    for (int off = 32; off > 0; off >>= 1)
        v += __shfl_down(v, off, 64);
    const int lane = threadIdx.x & 63;
    const int wave = threadIdx.x >> 6;
    if (lane == 0) lds[wave] = v;
    __syncthreads();
    if (threadIdx.x == 0) {
        float s = 0.0f;
        for (int w = 0; w < 4; ++w) s += lds[w];
        lds[0] = s;
    }
    __syncthreads();
    const float r = lds[0];
    __syncthreads();
    return r;
}

__device__ __forceinline__ void haar_quad(float a, float b, float c, float d,
                                          float& cA, float& cH, float& cV, float& cD) {
    const float sab = a + b, scd = c + d, dab = a - b, dcd = c - d;
    cA = 0.5f * (sab + scd);
    cH = 0.5f * (sab - scd);
    cV = 0.5f * (dab + dcd);
    cD = 0.5f * (dab - dcd);
}

// Legacy per-thread 8x8 version (used only on the never-taken correction path).
__device__ __forceinline__ float wavelet_block_loss(
        const float* __restrict__ blk, float t1, float t2, float t3) {
    float cA1[4][4];
    float s1 = 0.0f, s2 = 0.0f, s3 = 0.0f;
    #pragma unroll
    for (int rr = 0; rr < 4; ++rr) {
        const float4 r0a = *(const float4*)(blk + (size_t)(2 * rr) * W);
        const float4 r0b = *(const float4*)(blk + (size_t)(2 * rr) * W + 4);
        const float4 r1a = *(const float4*)(blk + (size_t)(2 * rr + 1) * W);
        const float4 r1b = *(const float4*)(blk + (size_t)(2 * rr + 1) * W + 4);
        const float top[8] = {r0a.x, r0a.y, r0a.z, r0a.w, r0b.x, r0b.y, r0b.z, r0b.w};
        const float bot[8] = {r1a.x, r1a.y, r1a.z, r1a.w, r1b.x, r1b.y, r1b.z, r1b.w};
        #pragma unroll
        for (int cc = 0; cc < 4; ++cc) {
            float cA, cH, cV, cD;
            haar_quad(top[2*cc], top[2*cc+1], bot[2*cc], bot[2*cc+1], cA, cH, cV, cD);
            s1 += fminf(fabsf(cH), t1) + fminf(fabsf(cV), t1) + fminf(fabsf(cD), t1);
            cA1[rr][cc] = cA;
        }
    }
    float cA2[2][2];
    #pragma unroll
    for (int rr = 0; rr < 2; ++rr)
        #pragma unroll
        for (int cc = 0; cc < 2; ++cc) {
            float cA, cH, cV, cD;
            haar_quad(cA1[2*rr][2*cc], cA1[2*rr][2*cc+1],
                      cA1[2*rr+1][2*cc], cA1[2*rr+1][2*cc+1], cA, cH, cV, cD);
            s2 += fminf(fabsf(cH), t2) + fminf(fabsf(cV), t2) + fminf(fabsf(cD), t2);
            cA2[rr][cc] = cA;
        }
    {
        float cA, cH, cV, cD;
        haar_quad(cA2[0][0], cA2[0][1], cA2[1][0], cA2[1][1], cA, cH, cV, cD);
        s3 = fminf(fabsf(cH), t3) + fminf(fabsf(cV), t3) + fminf(fabsf(cD), t3);
    }
    const float w1 = 1.0f / (9.0f * 65536.0f);
    const float w2 = 1.0f / (6.0f * 16384.0f);
    const float w3 = 1.0f / (3.0f * 4096.0f);
    return s1 * w1 + s2 * w2 + s3 * w3;
}

__global__ __launch_bounds__(256) void pass_a(const float* __restrict__ x,
                                              float* __restrict__ partials,
                                              uint32_t* __restrict__ ghist,
                                              float* __restrict__ out) {
    __shared__ uint32_t h[NBIN];
    __shared__ float lds[8];
    const int tid  = threadIdx.x;
    const int lane = tid & 63;
    const int wv   = tid >> 6;          // wave 0..3
    const int sub  = blockIdx.x;        // 0..15
    const int b    = blockIdx.y;        // 0..127

    h[tid] = 0u;
    h[tid + 256] = 0u;
    if (sub == 0 && b == 0 && tid < 2) out[tid] = 0.0f;   // init d_out
    __syncthreads();

    const float BASE = 40.0f / 400.0f;
    const float t3 = BASE * 2.0f, t2 = t3 * 0.5f, t1 = t3 * 0.25f;

    // Wave strip: 8 rows x 512 cols. Strip index R = sub*4 + wv (0..63).
    const int R = sub * 4 + wv;
    const float* strip = x + (size_t)b * W * W + (size_t)(R * 8) * W;

    float cA1A[4][2], cA1B[4][2];       // [row-pair rp][in-lane level-1 col]
    float s1 = 0.0f, s2 = 0.0f, s3 = 0.0f;

    #pragma unroll
    for (int rp = 0; rp < 4; ++rp) {
        const float* r0 = strip + (size_t)(2 * rp) * W;
        const float* r1 = strip + (size_t)(2 * rp + 1) * W;
        // perfectly lane-contiguous: lane i -> byte offset 16*i
        const float4 tA = *(const float4*)(r0 + 4 * lane);
        const float4 bA = *(const float4*)(r1 + 4 * lane);
        const float4 tB = *(const float4*)(r0 + 256 + 4 * lane);
        const float4 bB = *(const float4*)(r1 + 256 + 4 * lane);

        float cA, cH, cV, cD;
        haar_quad(tA.x, tA.y, bA.x, bA.y, cA, cH, cV, cD);
        s1 += fminf(fabsf(cH), t1) + fminf(fabsf(cV), t1) + fminf(fabsf(cD), t1);
        cA1A[rp][0] = cA;
        haar_quad(tA.z, tA.w, bA.z, bA.w, cA, cH, cV, cD);
        s1 += fminf(fabsf(cH), t1) + fminf(fabsf(cV), t1) + fminf(fabsf(cD), t1);
        cA1A[rp][1] = cA;
        haar_quad(tB.x, tB.y, bB.x, bB.y, cA, cH, cV, cD);
        s1 += fminf(fabsf(cH), t1) + fminf(fabsf(cV), t1) + fminf(fabsf(cD), t1);
        cA1B[rp][0] = cA;
        haar_quad(tB.z, tB.w, bB.z, bB.w, cA, cH, cV, cD);
        s1 += fminf(fabsf(cH), t1) + fminf(fabsf(cV), t1) + fminf(fabsf(cD), t1);
        cA1B[rp][1] = cA;
    }

    float cA2A[2], cA2B[2];             // level-2 cA, rows 0..1, in-lane col
    #pragma unroll
    for (int j = 0; j < 2; ++j) {
        float cA, cH, cV, cD;
        haar_quad(cA1A[2*j][0], cA1A[2*j][1], cA1A[2*j+1][0], cA1A[2*j+1][1],
                  cA, cH, cV, cD);
        s2 += fminf(fabsf(cH), t2) + fminf(fabsf(cV), t2) + fminf(fabsf(cD), t2);
        cA2A[j] = cA;
        haar_quad(cA1B[2*j][0], cA1B[2*j][1], cA1B[2*j+1][0], cA1B[2*j+1][1],
                  cA, cH, cV, cD);
        s2 += fminf(fabsf(cH), t2) + fminf(fabsf(cV), t2) + fminf(fabsf(cD), t2);
        cA2B[j] = cA;
    }

    // level-3: cols pair across adjacent lanes (2k, 2k+1).
    // Even lane computes the A-half quad, odd lane the B-half quad.
    // haar_quad(b,a,d,c) only negates cV,cD vs haar_quad(a,b,c,d), and we
    // only consume |coeff|, so each lane can use (own, partner) order.
    // Send the OTHER half's values so the receiver gets what it needs.
    {
        const float send0 = (lane & 1) ? cA2A[0] : cA2B[0];
        const float send1 = (lane & 1) ? cA2A[1] : cA2B[1];
        const float p0 = __shfl_xor(send0, 1, 64);
        const float p1 = __shfl_xor(send1, 1, 64);
        const float q0 = (lane & 1) ? cA2B[0] : cA2A[0];
        const float q2 = (lane & 1) ? cA2B[1] : cA2A[1];
        float cA, cH, cV, cD;
        haar_quad(q0, p0, q2, p1, cA, cH, cV, cD);
        const float aH = fabsf(cH), aV = fabsf(cV), aD = fabsf(cD);
        s3 += fminf(aH, t3) + fminf(aV, t3) + fminf(aD, t3);
        atomicAdd(&h[min((int)(aH * 256.0f), NBIN - 1)], 1u);
        atomicAdd(&h[min((int)(aV * 256.0f), NBIN - 1)], 1u);
        atomicAdd(&h[min((int)(aD * 256.0f), NBIN - 1)], 1u);
    }

    // level weights: 1/3·1/3/65536 (L1), 1/2·1/3/16384 (L2), 1/1·1/3/4096 (L3)
    const float w1 = 1.0f / (9.0f * 65536.0f);
    const float w2 = 1.0f / (6.0f * 16384.0f);
    const float w3 = 1.0f / (3.0f * 4096.0f);
    const float part = s1 * w1 + s2 * w2 + s3 * w3;

    const float tot = block_reduce_sum(part, lds);   // barriers fence h[] too
    if (tid == 0) partials[b * 16 + sub] = tot;

    // plain-store this block's complete sub-histogram (no memset needed)
    uint32_t* gh = ghist + ((size_t)b * 16 + sub) * NBIN;
    gh[tid] = h[tid];
    gh[tid + 256] = h[tid + 256];
}

// One wave per batch: sum 16 sub-hists, scan for order stats 6143/6144,
// sigma from bin midpoint, finalize loss.
__global__ __launch_bounds__(64) void pass_b(const uint32_t* __restrict__ ghist,
                                             const float* __restrict__ partials,
                                             const float* __restrict__ x,
                                             float* __restrict__ out) {
    const int b = blockIdx.x;
    const int lane = threadIdx.x;   // 0..63; owns bins [8*lane, 8*lane+8)
    uint32_t c[8] = {0, 0, 0, 0, 0, 0, 0, 0};

    // Fully unrolled: this pass is latency-bound (128 waves grid-wide);
    // let all 32 uint4 loads issue for maximum MLP.
    #pragma unroll
    for (int s = 0; s < 16; ++s) {
        const uint32_t* hb = ghist + ((size_t)b * 16 + s) * NBIN + lane * 8;
        const uint4 u0 = *(const uint4*)(hb);
        const uint4 u1 = *(const uint4*)(hb + 4);
        c[0] += u0.x; c[1] += u0.y; c[2] += u0.z; c[3] += u0.w;
        c[4] += u1.x; c[5] += u1.y; c[6] += u1.z; c[7] += u1.w;
    }

    uint32_t lane_sum = 0;
    #pragma unroll
    for (int j = 0; j < 8; ++j) lane_sum += c[j];

    // exclusive prefix of lane_sum across the wave
    uint32_t incl = lane_sum;
    #pragma unroll
    for (int off = 1; off < 64; off <<= 1) {
        const uint32_t v = __shfl_up(incl, off, 64);
        if (lane >= off) incl += v;
    }
    uint32_t run = incl - lane_sum;

    int bin1 = 0x7FFFFFFF, bin2 = 0x7FFFFFFF;
    #pragma unroll
    for (int j = 0; j < 8; ++j) {
        const uint32_t nxt = run + c[j];
        if (run < 6144u && nxt >= 6144u) bin1 = lane * 8 + j;
        if (run < 6145u && nxt >= 6145u) bin2 = lane * 8 + j;
        run = nxt;
    }
    #pragma unroll
    for (int off = 32; off > 0; off >>= 1) {
        bin1 = min(bin1, __shfl_down(bin1, off, 64));
        bin2 = min(bin2, __shfl_down(bin2, off, 64));
    }
    bin1 = __shfl(bin1, 0, 64);
    bin2 = __shfl(bin2, 0, 64);

    const float v1 = ((float)bin1 + 0.5f) * (1.0f / 256.0f);
    const float v2 = ((float)bin2 + 0.5f) * (1.0f / 256.0f);
    const float med = 0.5f * (v1 + v2);          // err <= 1/512 ~ 2e-3
    const float sig = med * (float)(1.0 / 0.6745);
    const float BASE = 40.0f / 400.0f;
    const float TTOP = BASE * 2.0f;
    const float t = fminf(fmaxf(sig * 2.5f, BASE * 0.5f), TTOP);

    float loss_b;
    if (t == TTOP) {
        float v = (lane < 16) ? partials[b * 16 + lane] : 0.0f;
        #pragma unroll
        for (int off = 32; off > 0; off >>= 1) v += __shfl_down(v, off, 64);
        loss_b = v;
    } else {
        // correction: recompute this batch with the true thresholds (rare)
        float part = 0.0f;
        #pragma unroll 1
        for (int k = 0; k < 64; ++k) {
            const int p = k * 64 + lane;
            const int i3 = p >> 6, j3 = p & 63;
            const float* blk = x + (size_t)b * W * W + (size_t)(i3 * 8) * W + j3 * 8;
            part += wavelet_block_loss(blk, t * 0.25f, t * 0.5f, t);
        }
        #pragma unroll
        for (int off = 32; off > 0; off >>= 1) part += __shfl_down(part, off, 64);
        loss_b = part;
    }

    if (lane == 0) {
        atomicAdd(&out[0], loss_b * (1.0f / (float)BATCH));
        atomicAdd(&out[1], sig * (1.0f / (float)BATCH));
    }
}

extern "C" void kernel_launch(void* const* d_in, const int* in_sizes, int n_in,
                              void* d_out, int out_size, void* d_ws, size_t ws_size,
                              hipStream_t stream) {
    const float* x = (const float*)d_in[0];
    float* ws = (float*)d_ws;
    float* partials = ws;                          // 2048 floats
    uint32_t* ghist = (uint32_t*)(ws + 2048);      // 128*16*512 u32 = 4 MB

    dim3 grid(16, BATCH);
    pass_a<<<grid, 256, 0, stream>>>(x, partials, ghist, (float*)d_out);
    pass_b<<<BATCH, 64, 0, stream>>>(ghist, partials, x, (float*)d_out);
}

// Round 2
// 191.095 us; speedup vs baseline: 1.0055x; 1.0055x over previous
//
#include <hip/hip_runtime.h>
#include <stdint.h>

// WaveletSparsityPrior: 3-level Haar, loss = sum_lvl w_lvl * mean min(|c|, t_lvl)
// Two dispatches: pass_a -> pass_b (no memset: sub-histograms are plain-stored).
//
// R1 finding (rocprof): measured dur_us is dominated by harness-side 512 MiB
// workspace poison fills (~80 us each at 83-86% HBM peak) + reset dispatches;
// pass_a/pass_b are below the 78 us profiling cutoff (expected ~25-35 us
// combined vs a ~23 us BW floor). This round: deepen pass_a's memory-level
// parallelism (batch 8 float4 loads ahead of compute, bit-identical order)
// and hoist pass_b's partials load; if dur_us doesn't move, the remaining
// time is harness-fixed and we are at the effective roofline.
//
//  pass_a (grid 16x128, 256 thr): each WAVE owns an 8-row x 512-col strip.
//    All global loads are lane-contiguous float4 (lane i -> byte 16*i), Haar
//    tree in registers: level-1/2 in-lane, level-3 via shfl_xor(1) with the
//    work split even-lane=A-half / odd-lane=B-half (|coeff| invariant under
//    the column swap, so all 64 lanes are active). Per-block 512-bin LDS
//    histogram of |level-3 details| plain-stored to ghist[b][sub][512]
//    (overwrites 0xAA poison -> no memset needed). Block (0,0) zeroes d_out.
//    Speculative t = 0.2 (clip top) -> exact loss because sigma~1.0 ->
//    2.5*sigma clips (verified absmax=0 across sessions).
//  pass_b (128 blocks x 64): sum 16 sub-hists (fully unrolled, latency-bound
//    at 0.5 wave/CU), scan for median bin -> sigma (bin-midpoint err <= 2e-3
//    << 2e-2 threshold) -> t -> finalize via 2 fp32 atomicAdds. Correction
//    recompute only if t != 0.2 (never taken for this input).
//
// ws layout: f32 [0,2048) partials[b*16+sub]; u32 [2048, +128*16*512) ghist.

static constexpr int BATCH = 128;
static constexpr int W = 512;
static constexpr int NBIN = 512;      // bin width 1/256 over [0,2)

__device__ __forceinline__ float block_reduce_sum(float v, float* lds) {
    #pragma unroll
    for (int off = 32; off > 0; off >>= 1)
        v += __shfl_down(v, off, 64);
    const int lane = threadIdx.x & 63;
    const int wave = threadIdx.x >> 6;
    if (lane == 0) lds[wave] = v;
    __syncthreads();
    if (threadIdx.x == 0) {
        float s = 0.0f;
        for (int w = 0; w < 4; ++w) s += lds[w];
        lds[0] = s;
    }
    __syncthreads();
    const float r = lds[0];
    __syncthreads();
    return r;
}

__device__ __forceinline__ void haar_quad(float a, float b, float c, float d,
                                          float& cA, float& cH, float& cV, float& cD) {
    const float sab = a + b, scd = c + d, dab = a - b, dcd = c - d;
    cA = 0.5f * (sab + scd);
    cH = 0.5f * (sab - scd);
    cV = 0.5f * (dab + dcd);
    cD = 0.5f * (dab - dcd);
}

// Legacy per-thread 8x8 version (used only on the never-taken correction path).
__device__ __forceinline__ float wavelet_block_loss(
        const float* __restrict__ blk, float t1, float t2, float t3) {
    float cA1[4][4];
    float s1 = 0.0f, s2 = 0.0f, s3 = 0.0f;
    #pragma unroll
    for (int rr = 0; rr < 4; ++rr) {
        const float4 r0a = *(const float4*)(blk + (size_t)(2 * rr) * W);
        const float4 r0b = *(const float4*)(blk + (size_t)(2 * rr) * W + 4);
        const float4 r1a = *(const float4*)(blk + (size_t)(2 * rr + 1) * W);
        const float4 r1b = *(const float4*)(blk + (size_t)(2 * rr + 1) * W + 4);
        const float top[8] = {r0a.x, r0a.y, r0a.z, r0a.w, r0b.x, r0b.y, r0b.z, r0b.w};
        const float bot[8] = {r1a.x, r1a.y, r1a.z, r1a.w, r1b.x, r1b.y, r1b.z, r1b.w};
        #pragma unroll
        for (int cc = 0; cc < 4; ++cc) {
            float cA, cH, cV, cD;
            haar_quad(top[2*cc], top[2*cc+1], bot[2*cc], bot[2*cc+1], cA, cH, cV, cD);
            s1 += fminf(fabsf(cH), t1) + fminf(fabsf(cV), t1) + fminf(fabsf(cD), t1);
            cA1[rr][cc] = cA;
        }
    }
    float cA2[2][2];
    #pragma unroll
    for (int rr = 0; rr < 2; ++rr)
        #pragma unroll
        for (int cc = 0; cc < 2; ++cc) {
            float cA, cH, cV, cD;
            haar_quad(cA1[2*rr][2*cc], cA1[2*rr][2*cc+1],
                      cA1[2*rr+1][2*cc], cA1[2*rr+1][2*cc+1], cA, cH, cV, cD);
            s2 += fminf(fabsf(cH), t2) + fminf(fabsf(cV), t2) + fminf(fabsf(cD), t2);
            cA2[rr][cc] = cA;
        }
    {
        float cA, cH, cV, cD;
        haar_quad(cA2[0][0], cA2[0][1], cA2[1][0], cA2[1][1], cA, cH, cV, cD);
        s3 = fminf(fabsf(cH), t3) + fminf(fabsf(cV), t3) + fminf(fabsf(cD), t3);
    }
    const float w1 = 1.0f / (9.0f * 65536.0f);
    const float w2 = 1.0f / (6.0f * 16384.0f);
    const float w3 = 1.0f / (3.0f * 4096.0f);
    return s1 * w1 + s2 * w2 + s3 * w3;
}

__global__ __launch_bounds__(256) void pass_a(const float* __restrict__ x,
                                              float* __restrict__ partials,
                                              uint32_t* __restrict__ ghist,
                                              float* __restrict__ out) {
    __shared__ uint32_t h[NBIN];
    __shared__ float lds[8];
    const int tid  = threadIdx.x;
    const int lane = tid & 63;
    const int wv   = tid >> 6;          // wave 0..3
    const int sub  = blockIdx.x;        // 0..15
    const int b    = blockIdx.y;        // 0..127

    h[tid] = 0u;
    h[tid + 256] = 0u;
    if (sub == 0 && b == 0 && tid < 2) out[tid] = 0.0f;   // init d_out
    __syncthreads();

    const float BASE = 40.0f / 400.0f;
    const float t3 = BASE * 2.0f, t2 = t3 * 0.5f, t1 = t3 * 0.25f;

    // Wave strip: 8 rows x 512 cols. Strip index R = sub*4 + wv (0..63).
    const int R = sub * 4 + wv;
    const float* strip = x + (size_t)b * W * W + (size_t)(R * 8) * W;

    float cA1A[4][2], cA1B[4][2];       // [row-pair rp][in-lane level-1 col]
    float s1 = 0.0f, s2 = 0.0f, s3 = 0.0f;

    // Issue loads in batches of 8 float4 (two row-pairs) so 8 independent
    // global_load_dwordx4 are in flight before the first dependent use.
    // Compute order (and thus fp32 accumulation order) is unchanged ->
    // bit-identical to the per-row-pair version.
    #pragma unroll
    for (int half = 0; half < 2; ++half) {
        float4 ld[2][4];    // [rp within half][tA,bA,tB,bB]
        #pragma unroll
        for (int q = 0; q < 2; ++q) {
            const int rp = half * 2 + q;
            const float* r0 = strip + (size_t)(2 * rp) * W;
            const float* r1 = strip + (size_t)(2 * rp + 1) * W;
            // perfectly lane-contiguous: lane i -> byte offset 16*i
            ld[q][0] = *(const float4*)(r0 + 4 * lane);
            ld[q][1] = *(const float4*)(r1 + 4 * lane);
            ld[q][2] = *(const float4*)(r0 + 256 + 4 * lane);
            ld[q][3] = *(const float4*)(r1 + 256 + 4 * lane);
        }
        #pragma unroll
        for (int q = 0; q < 2; ++q) {
            const int rp = half * 2 + q;
            const float4 tA = ld[q][0], bA = ld[q][1];
            const float4 tB = ld[q][2], bB = ld[q][3];

            float cA, cH, cV, cD;
            haar_quad(tA.x, tA.y, bA.x, bA.y, cA, cH, cV, cD);
            s1 += fminf(fabsf(cH), t1) + fminf(fabsf(cV), t1) + fminf(fabsf(cD), t1);
            cA1A[rp][0] = cA;
            haar_quad(tA.z, tA.w, bA.z, bA.w, cA, cH, cV, cD);
            s1 += fminf(fabsf(cH), t1) + fminf(fabsf(cV), t1) + fminf(fabsf(cD), t1);
            cA1A[rp][1] = cA;
            haar_quad(tB.x, tB.y, bB.x, bB.y, cA, cH, cV, cD);
            s1 += fminf(fabsf(cH), t1) + fminf(fabsf(cV), t1) + fminf(fabsf(cD), t1);
            cA1B[rp][0] = cA;
            haar_quad(tB.z, tB.w, bB.z, bB.w, cA, cH, cV, cD);
            s1 += fminf(fabsf(cH), t1) + fminf(fabsf(cV), t1) + fminf(fabsf(cD), t1);
            cA1B[rp][1] = cA;
        }
    }

    float cA2A[2], cA2B[2];             // level-2 cA, rows 0..1, in-lane col
    #pragma unroll
    for (int j = 0; j < 2; ++j) {
        float cA, cH, cV, cD;
        haar_quad(cA1A[2*j][0], cA1A[2*j][1], cA1A[2*j+1][0], cA1A[2*j+1][1],
                  cA, cH, cV, cD);
        s2 += fminf(fabsf(cH), t2) + fminf(fabsf(cV), t2) + fminf(fabsf(cD), t2);
        cA2A[j] = cA;
        haar_quad(cA1B[2*j][0], cA1B[2*j][1], cA1B[2*j+1][0], cA1B[2*j+1][1],
                  cA, cH, cV, cD);
        s2 += fminf(fabsf(cH), t2) + fminf(fabsf(cV), t2) + fminf(fabsf(cD), t2);
        cA2B[j] = cA;
    }

    // level-3: cols pair across adjacent lanes (2k, 2k+1).
    // Even lane computes the A-half quad, odd lane the B-half quad.
    // haar_quad(b,a,d,c) only negates cV,cD vs haar_quad(a,b,c,d), and we
    // only consume |coeff|, so each lane can use (own, partner) order.
    // Send the OTHER half's values so the receiver gets what it needs.
    {
        const float send0 = (lane & 1) ? cA2A[0] : cA2B[0];
        const float send1 = (lane & 1) ? cA2A[1] : cA2B[1];
        const float p0 = __shfl_xor(send0, 1, 64);
        const float p1 = __shfl_xor(send1, 1, 64);
        const float q0 = (lane & 1) ? cA2B[0] : cA2A[0];
        const float q2 = (lane & 1) ? cA2B[1] : cA2A[1];
        float cA, cH, cV, cD;
        haar_quad(q0, p0, q2, p1, cA, cH, cV, cD);
        const float aH = fabsf(cH), aV = fabsf(cV), aD = fabsf(cD);
        s3 += fminf(aH, t3) + fminf(aV, t3) + fminf(aD, t3);
        atomicAdd(&h[min((int)(aH * 256.0f), NBIN - 1)], 1u);
        atomicAdd(&h[min((int)(aV * 256.0f), NBIN - 1)], 1u);
        atomicAdd(&h[min((int)(aD * 256.0f), NBIN - 1)], 1u);
    }

    // level weights: 1/3·1/3/65536 (L1), 1/2·1/3/16384 (L2), 1/1·1/3/4096 (L3)
    const float w1 = 1.0f / (9.0f * 65536.0f);
    const float w2 = 1.0f / (6.0f * 16384.0f);
    const float w3 = 1.0f / (3.0f * 4096.0f);
    const float part = s1 * w1 + s2 * w2 + s3 * w3;

    const float tot = block_reduce_sum(part, lds);   // barriers fence h[] too
    if (tid == 0) partials[b * 16 + sub] = tot;

    // plain-store this block's complete sub-histogram (no memset needed)
    uint32_t* gh = ghist + ((size_t)b * 16 + sub) * NBIN;
    gh[tid] = h[tid];
    gh[tid + 256] = h[tid + 256];
}

// One wave per batch: sum 16 sub-hists, scan for order stats 6143/6144,
// sigma from bin midpoint, finalize loss.
__global__ __launch_bounds__(64) void pass_b(const uint32_t* __restrict__ ghist,
                                             const float* __restrict__ partials,
                                             const float* __restrict__ x,
                                             float* __restrict__ out) {
    const int b = blockIdx.x;
    const int lane = threadIdx.x;   // 0..63; owns bins [8*lane, 8*lane+8)

    // Hoist the partials load so its latency overlaps the histogram burst.
    const float pval = (lane < 16) ? partials[b * 16 + lane] : 0.0f;

    uint32_t c[8] = {0, 0, 0, 0, 0, 0, 0, 0};

    // Fully unrolled: this pass is latency-bound (128 waves grid-wide);
    // let all 32 uint4 loads issue for maximum MLP.
    #pragma unroll
    for (int s = 0; s < 16; ++s) {
        const uint32_t* hb = ghist + ((size_t)b * 16 + s) * NBIN + lane * 8;
        const uint4 u0 = *(const uint4*)(hb);
        const uint4 u1 = *(const uint4*)(hb + 4);
        c[0] += u0.x; c[1] += u0.y; c[2] += u0.z; c[3] += u0.w;
        c[4] += u1.x; c[5] += u1.y; c[6] += u1.z; c[7] += u1.w;
    }

    uint32_t lane_sum = 0;
    #pragma unroll
    for (int j = 0; j < 8; ++j) lane_sum += c[j];

    // exclusive prefix of lane_sum across the wave
    uint32_t incl = lane_sum;
    #pragma unroll
    for (int off = 1; off < 64; off <<= 1) {
        const uint32_t v = __shfl_up(incl, off, 64);
        if (lane >= off) incl += v;
    }
    uint32_t run = incl - lane_sum;

    int bin1 = 0x7FFFFFFF, bin2 = 0x7FFFFFFF;
    #pragma unroll
    for (int j = 0; j < 8; ++j) {
        const uint32_t nxt = run + c[j];
        if (run < 6144u && nxt >= 6144u) bin1 = lane * 8 + j;
        if (run < 6145u && nxt >= 6145u) bin2 = lane * 8 + j;
        run = nxt;
    }
    #pragma unroll
    for (int off = 32; off > 0; off >>= 1) {
        bin1 = min(bin1, __shfl_down(bin1, off, 64));
        bin2 = min(bin2, __shfl_down(bin2, off, 64));
    }
    bin1 = __shfl(bin1, 0, 64);
    bin2 = __shfl(bin2, 0, 64);

    const float v1 = ((float)bin1 + 0.5f) * (1.0f / 256.0f);
    const float v2 = ((float)bin2 + 0.5f) * (1.0f / 256.0f);
    const float med = 0.5f * (v1 + v2);          // err <= 1/512 ~ 2e-3
    const float sig = med * (float)(1.0 / 0.6745);
    const float BASE = 40.0f / 400.0f;
    const float TTOP = BASE * 2.0f;
    const float t = fminf(fmaxf(sig * 2.5f, BASE * 0.5f), TTOP);

    float loss_b;
    if (t == TTOP) {
        float v = pval;
        #pragma unroll
        for (int off = 32; off > 0; off >>= 1) v += __shfl_down(v, off, 64);
        loss_b = v;
    } else {
        // correction: recompute this batch with the true thresholds (rare)
        float part = 0.0f;
        #pragma unroll 1
        for (int k = 0; k < 64; ++k) {
            const int p = k * 64 + lane;
            const int i3 = p >> 6, j3 = p & 63;
            const float* blk = x + (size_t)b * W * W + (size_t)(i3 * 8) * W + j3 * 8;
            part += wavelet_block_loss(blk, t * 0.25f, t * 0.5f, t);
        }
        #pragma unroll
        for (int off = 32; off > 0; off >>= 1) part += __shfl_down(part, off, 64);
        loss_b = part;
    }

    if (lane == 0) {
        atomicAdd(&out[0], loss_b * (1.0f / (float)BATCH));
        atomicAdd(&out[1], sig * (1.0f / (float)BATCH));
    }
}

extern "C" void kernel_launch(void* const* d_in, const int* in_sizes, int n_in,
                              void* d_out, int out_size, void* d_ws, size_t ws_size,
                              hipStream_t stream) {
    const float* x = (const float*)d_in[0];
    float* ws = (float*)d_ws;
    float* partials = ws;                          // 2048 floats
    uint32_t* ghist = (uint32_t*)(ws + 2048);      // 128*16*512 u32 = 4 MB

    dim3 grid(16, BATCH);
    pass_a<<<grid, 256, 0, stream>>>(x, partials, ghist, (float*)d_out);
    pass_b<<<BATCH, 64, 0, stream>>>(ghist, partials, x, (float*)d_out);
}